// Round 2
// baseline (564.520 us; speedup 1.0000x reference)
//
#include <hip/hip_runtime.h>
#include <hip/hip_bf16.h>

#define BB_ 64
#define NN_ 32
#define II_ 1152
#define DD_ 16
#define KK_ 8

constexpr int NB    = 4;               // batch tile per block
constexpr int IPW   = 9;               // i's per wave
constexpr int WAVES = 4;
constexpr int CHUNK_I = WAVES * IPW;   // 36
constexpr int NIC   = II_ / CHUNK_I;   // 32 i-chunks
constexpr int NBG   = BB_ / NB;        // 16 b-groups
constexpr int SVD   = BB_ * NN_ * DD_; // 32768 elems of s/v

// MODE 0: c = 1/32 (iteration 0). MODE 1: c = softmax_n(u_hat . veff)
template <int MODE>
__global__ __launch_bounds__(256) void route_kernel(
    const float* __restrict__ W, const float* __restrict__ x,
    const float* __restrict__ veff, float* __restrict__ s_out)
{
    int bid = blockIdx.x;
    // XCD-aware swizzle: same i-chunk -> same XCD (W slice stays L2-hot)
    int xcd = bid & 7;
    int k2  = bid >> 3;          // 0..63
    int ic  = xcd + 8 * (k2 >> 4);  // 0..31
    int bg  = k2 & 15;              // 0..15
    int b0  = bg * NB;

    int tid  = threadIdx.x;
    int wave = tid >> 6;
    int lane = tid & 63;
    int n    = lane & 31;
    int d0   = (lane >> 5) * 8;

    float sacc[NB][8];
#pragma unroll
    for (int bb = 0; bb < NB; ++bb)
#pragma unroll
        for (int j = 0; j < 8; ++j) sacc[bb][j] = 0.f;

    float ve[NB][8];
    if constexpr (MODE == 1) {
#pragma unroll
        for (int bb = 0; bb < NB; ++bb) {
            const float* vp = veff + ((b0 + bb) * NN_ + n) * DD_ + d0;
            float4 a = *(const float4*)vp;
            float4 c4 = *(const float4*)(vp + 4);
            ve[bb][0] = a.x;  ve[bb][1] = a.y;  ve[bb][2] = a.z;  ve[bb][3] = a.w;
            ve[bb][4] = c4.x; ve[bb][5] = c4.y; ve[bb][6] = c4.z; ve[bb][7] = c4.w;
        }
    }

    int ibase = ic * CHUNK_I + wave * IPW;
    for (int t = 0; t < IPW; ++t) {
        int i = ibase + t;

        // x[b0..b0+NB, i, 0..7] (wave-uniform addresses -> broadcast loads)
        float xr[NB][8];
#pragma unroll
        for (int bb = 0; bb < NB; ++bb) {
            const float* xp = x + ((b0 + bb) * II_ + i) * KK_;
            float4 a = *(const float4*)xp;
            float4 c4 = *(const float4*)(xp + 4);
            xr[bb][0] = a.x;  xr[bb][1] = a.y;  xr[bb][2] = a.z;  xr[bb][3] = a.w;
            xr[bb][4] = c4.x; xr[bb][5] = c4.y; xr[bb][6] = c4.z; xr[bb][7] = c4.w;
        }

        // u_hat[bb][j] for d = d0+j ; W[n,i,d,k] contiguous in (d,k)
        float uh[NB][8];
        const float* wp = W + (((n * II_ + i) * DD_ + d0) * KK_);
#pragma unroll
        for (int j = 0; j < 8; ++j) {
            float4 w0 = *(const float4*)(wp + j * KK_);
            float4 w1 = *(const float4*)(wp + j * KK_ + 4);
#pragma unroll
            for (int bb = 0; bb < NB; ++bb) {
                uh[bb][j] = w0.x * xr[bb][0] + w0.y * xr[bb][1] +
                            w0.z * xr[bb][2] + w0.w * xr[bb][3] +
                            w1.x * xr[bb][4] + w1.y * xr[bb][5] +
                            w1.z * xr[bb][6] + w1.w * xr[bb][7];
            }
        }

#pragma unroll
        for (int bb = 0; bb < NB; ++bb) {
            float c;
            if constexpr (MODE == 0) {
                c = 1.0f / 32.0f;
            } else {
                // logit = telescoped b = sum_d uh*veff (full D via lane^32)
                float blp = 0.f;
#pragma unroll
                for (int j = 0; j < 8; ++j) blp += uh[bb][j] * ve[bb][j];
                blp += __shfl_xor(blp, 32);
                // softmax over n: full 32-value reduce inside each 32-lane half
                float mx = blp;
#pragma unroll
                for (int st = 16; st >= 1; st >>= 1) mx = fmaxf(mx, __shfl_xor(mx, st));
                float e = __expf(blp - mx);
                float sm = e;
#pragma unroll
                for (int st = 16; st >= 1; st >>= 1) sm += __shfl_xor(sm, st);
                c = e / sm;
            }
#pragma unroll
            for (int j = 0; j < 8; ++j) sacc[bb][j] += c * uh[bb][j];
        }
    }

    // flush partial s to global
#pragma unroll
    for (int bb = 0; bb < NB; ++bb) {
        float* sp = s_out + ((b0 + bb) * NN_ + n) * DD_ + d0;
#pragma unroll
        for (int j = 0; j < 8; ++j) unsafeAtomicAdd(sp + j, sacc[bb][j]);
    }
}

// OUT_MODE 0: vout = squash(s); s=0
// OUT_MODE 1: vout = vprev + squash(s); s=0
// OUT_MODE 2: out  = f32(sigmoid(squash(s)*dw + db))
template <int OUT_MODE>
__global__ void squash_kernel(float* __restrict__ s, const float* __restrict__ vprev,
                              float* __restrict__ vout,
                              const float* __restrict__ dw, const float* __restrict__ db,
                              float* __restrict__ out)
{
    int idx = blockIdx.x * blockDim.x + threadIdx.x;
    if (idx >= SVD) return;
    float ss = s[idx];
    float sq = ss * ss;
    float scale = sq / (1.f + sq) / sqrtf(sq + 1e-7f);
    float v = scale * ss;
    if constexpr (OUT_MODE == 0) {
        vout[idx] = v;
        s[idx] = 0.f;
    } else if constexpr (OUT_MODE == 1) {
        vout[idx] = vprev[idx] + v;
        s[idx] = 0.f;
    } else {
        float z = v * dw[0] + db[0];
        out[idx] = 1.f / (1.f + __expf(-z));
    }
}

extern "C" void kernel_launch(void* const* d_in, const int* in_sizes, int n_in,
                              void* d_out, int out_size, void* d_ws, size_t ws_size,
                              hipStream_t stream)
{
    const float* x  = (const float*)d_in[0];
    const float* W  = (const float*)d_in[1];
    const float* dw = (const float*)d_in[2];
    const float* db = (const float*)d_in[3];
    float* out = (float*)d_out;

    float* s  = (float*)d_ws;     // [B,N,D] accumulator
    float* vA = s + SVD;          // v0
    float* vB = vA + SVD;         // v0+v1

    hipMemsetAsync(s, 0, SVD * sizeof(float), stream);

    dim3 blk(256);
    dim3 grid(NIC * NBG);         // 512 blocks
    int sq_blocks = (SVD + 255) / 256;

    // iter 0: c = 1/32
    route_kernel<0><<<grid, blk, 0, stream>>>(W, x, nullptr, s);
    squash_kernel<0><<<sq_blocks, 256, 0, stream>>>(s, nullptr, vA, nullptr, nullptr, nullptr);
    // iter 1: logits = uh.v0
    route_kernel<1><<<grid, blk, 0, stream>>>(W, x, vA, s);
    squash_kernel<1><<<sq_blocks, 256, 0, stream>>>(s, vA, vB, nullptr, nullptr, nullptr);
    // iter 2: logits = uh.(v0+v1)
    route_kernel<1><<<grid, blk, 0, stream>>>(W, x, vB, s);
    squash_kernel<2><<<sq_blocks, 256, 0, stream>>>(s, nullptr, nullptr, dw, db, out);
}

// Round 3
// 142.134 us; speedup vs baseline: 3.9717x; 3.9717x over previous
//
#include <hip/hip_runtime.h>

constexpr int B_ = 64, N_ = 32, I_ = 1152, D_ = 16, K_ = 8;
constexpr int SVD = B_ * N_ * D_;        // 32768 elems of s/v
constexpr int SLICE_W = N_ * D_ * K_;    // 4096 floats = 16KB per-i W slice

// Block: 256 threads = 4 waves. Wave w handles 4 batches (bg*16 + w*4 + bb).
// All waves share the same i (W slice staged once in LDS per i).
// lane -> (n = lane&31, d-half h = lane>>5). Softmax fully in-wave.
// MODE 0: c = 1/32. MODE 1: c = softmax_n(u_hat . veff)  [telescoped logits]
// FLUSH 0: plain store to partial[ic*4+bg]  FLUSH 1: atomicAdd into s (fallback)
template <int MODE, int FLUSH>
__global__ __launch_bounds__(256, 2) void route2(
    const float* __restrict__ W, const float* __restrict__ x,
    const float* __restrict__ veff, float* __restrict__ dst,
    int nic, int ic_len)
{
    __shared__ __align__(16) float wlds[2][SLICE_W];

    int bid = blockIdx.x;
    int ic, bg;
    if ((nic & 7) == 0) {
        // XCD-contiguous ic ranges: per-XCD W footprint fits its 4MB L2
        int x8 = bid & 7, r = bid >> 3, icpx = nic >> 3;
        ic = x8 * icpx + (r % icpx);
        bg = r / icpx;
    } else {
        ic = bid >> 2; bg = bid & 3;
    }

    int tid  = threadIdx.x;
    int wave = tid >> 6, lane = tid & 63;
    int n = lane & 31, d0 = (lane >> 5) * 8;
    int bB = bg * 16 + wave * 4;
    int rsw = (n & 7) << 2;          // read-side LDS word swizzle (byte>>2)

    float sacc[4][8];
#pragma unroll
    for (int bb = 0; bb < 4; ++bb)
#pragma unroll
        for (int j = 0; j < 8; ++j) sacc[bb][j] = 0.f;

    float ve[4][8];
    if constexpr (MODE == 1) {
#pragma unroll
        for (int bb = 0; bb < 4; ++bb) {
            const float* vp = veff + ((bB + bb) * N_ + n) * D_ + d0;
            float4 a = *(const float4*)vp;
            float4 c4 = *(const float4*)(vp + 4);
            ve[bb][0] = a.x;  ve[bb][1] = a.y;  ve[bb][2] = a.z;  ve[bb][3] = a.w;
            ve[bb][4] = c4.x; ve[bb][5] = c4.y; ve[bb][6] = c4.z; ve[bb][7] = c4.w;
        }
    }

    // --- W staging: 16KB slice, 256 threads x 4 float4 each, coalesced ---
    int nsl = tid >> 3;              // n-slice this thread stages
    int p0  = tid & 7;               // float4 piece base
    const float* wg = W + (size_t)nsl * (I_ * D_ * K_);
    int lw_base = nsl * 128;
    int lsw = (nsl & 7) << 2;        // write-side swizzle (same involution)
    float4 st[4];

    int i0 = ic * ic_len;
    auto stage_load = [&](int i) {
#pragma unroll
        for (int r = 0; r < 4; ++r)
            st[r] = *(const float4*)(wg + i * 128 + (p0 + 8 * r) * 4);
    };
    auto stage_write = [&](int buf) {
#pragma unroll
        for (int r = 0; r < 4; ++r) {
            int w = (lw_base + (p0 + 8 * r) * 4) ^ lsw;
            *(float4*)&wlds[buf][w] = st[r];
        }
    };

    stage_load(i0);
    stage_write(0);

    for (int t = 0; t < ic_len; ++t) {
        __syncthreads();                       // stage of buf(t&1) visible
        if (t + 1 < ic_len) stage_load(i0 + t + 1);   // overlap with compute
        int buf = t & 1;
        int i = i0 + t;

        // x[b, i, :] — wave-uniform broadcast loads
        float xr[4][8];
#pragma unroll
        for (int bb = 0; bb < 4; ++bb) {
            const float* xp = x + ((bB + bb) * I_ + i) * K_;
            float4 a = *(const float4*)xp;
            float4 c4 = *(const float4*)(xp + 4);
            xr[bb][0] = a.x;  xr[bb][1] = a.y;  xr[bb][2] = a.z;  xr[bb][3] = a.w;
            xr[bb][4] = c4.x; xr[bb][5] = c4.y; xr[bb][6] = c4.z; xr[bb][7] = c4.w;
        }

        float uh[4][8];
#pragma unroll
        for (int j = 0; j < 8; ++j) {
            int w0 = n * 128 + (d0 + j) * 8;
            float4 wa = *(const float4*)&wlds[buf][(w0) ^ rsw];
            float4 wb = *(const float4*)&wlds[buf][(w0 + 4) ^ rsw];
#pragma unroll
            for (int bb = 0; bb < 4; ++bb) {
                uh[bb][j] = wa.x * xr[bb][0] + wa.y * xr[bb][1] +
                            wa.z * xr[bb][2] + wa.w * xr[bb][3] +
                            wb.x * xr[bb][4] + wb.y * xr[bb][5] +
                            wb.z * xr[bb][6] + wb.w * xr[bb][7];
            }
        }

#pragma unroll
        for (int bb = 0; bb < 4; ++bb) {
            float c;
            if constexpr (MODE == 0) {
                c = 1.0f / 32.0f;
            } else {
                float blp = 0.f;
#pragma unroll
                for (int j = 0; j < 8; ++j) blp += uh[bb][j] * ve[bb][j];
                blp += __shfl_xor(blp, 32);    // full-D dot
                float mx = blp;
#pragma unroll
                for (int s2 = 16; s2 >= 1; s2 >>= 1) mx = fmaxf(mx, __shfl_xor(mx, s2));
                float e = __expf(blp - mx);
                float sm = e;
#pragma unroll
                for (int s2 = 16; s2 >= 1; s2 >>= 1) sm += __shfl_xor(sm, s2);
                c = e / sm;
            }
#pragma unroll
            for (int j = 0; j < 8; ++j) sacc[bb][j] += c * uh[bb][j];
        }

        if (t + 1 < ic_len) stage_write((t + 1) & 1);
    }

    if constexpr (FLUSH == 0) {
        // partial[(ic*4+bg)][wb=wave*4+bb][n][d]
        float* pb = dst + ((size_t)(ic * 4 + bg)) * 8192 + (wave * 4) * 512 + n * 16 + d0;
#pragma unroll
        for (int bb = 0; bb < 4; ++bb) {
            float4 a = {sacc[bb][0], sacc[bb][1], sacc[bb][2], sacc[bb][3]};
            float4 c4 = {sacc[bb][4], sacc[bb][5], sacc[bb][6], sacc[bb][7]};
            *(float4*)(pb + bb * 512) = a;
            *(float4*)(pb + bb * 512 + 4) = c4;
        }
    } else {
#pragma unroll
        for (int bb = 0; bb < 4; ++bb) {
            float* sp = dst + ((bB + bb) * N_ + n) * D_ + d0;
#pragma unroll
            for (int j = 0; j < 8; ++j) unsafeAtomicAdd(sp + j, sacc[bb][j]);
        }
    }
}

// Fused reduce(partials over nic) + squash (+ v-chain / final sigmoid).
// OUT_MODE 0: vout=squash  1: vout=vprev+squash  2: out=sigmoid(squash*dw+db)
template <int OUT_MODE>
__global__ void squash2(const float* __restrict__ partial, int nic,
                        const float* __restrict__ vprev, float* __restrict__ vout,
                        const float* __restrict__ dw, const float* __restrict__ db,
                        float* __restrict__ out)
{
    int idx = blockIdx.x * 64 + threadIdx.x;   // grid 512 x 64 = 32768
    int d = idx & 15, n = (idx >> 4) & 31, b = idx >> 9;
    int bg = b >> 4, wb = b & 15;
    const float* p = partial + bg * 8192 + wb * 512 + n * 16 + d;
    float s0 = 0.f, s1 = 0.f, s2 = 0.f, s3 = 0.f;
    int ic = 0;
    for (; ic + 4 <= nic; ic += 4) {
        s0 += p[(size_t)(ic + 0) * 32768];
        s1 += p[(size_t)(ic + 1) * 32768];
        s2 += p[(size_t)(ic + 2) * 32768];
        s3 += p[(size_t)(ic + 3) * 32768];
    }
    for (; ic < nic; ++ic) s0 += p[(size_t)ic * 32768];
    float ss = (s0 + s1) + (s2 + s3);

    float sq = ss * ss;
    float scale = sq / (1.f + sq) / sqrtf(sq + 1e-7f);
    float v = scale * ss;
    if constexpr (OUT_MODE == 0) {
        vout[idx] = v;
    } else if constexpr (OUT_MODE == 1) {
        vout[idx] = vprev[idx] + v;
    } else {
        float z = v * dw[0] + db[0];
        out[idx] = 1.f / (1.f + __expf(-z));
    }
}

// Atomic-path squash (fallback): reads s, zeroes it for the next iteration.
template <int OUT_MODE>
__global__ void squashA(float* __restrict__ s, const float* __restrict__ vprev,
                        float* __restrict__ vout,
                        const float* __restrict__ dw, const float* __restrict__ db,
                        float* __restrict__ out)
{
    int idx = blockIdx.x * blockDim.x + threadIdx.x;
    if (idx >= SVD) return;
    float ss = s[idx];
    float sq = ss * ss;
    float scale = sq / (1.f + sq) / sqrtf(sq + 1e-7f);
    float v = scale * ss;
    if constexpr (OUT_MODE == 0) { vout[idx] = v; s[idx] = 0.f; }
    else if constexpr (OUT_MODE == 1) { vout[idx] = vprev[idx] + v; s[idx] = 0.f; }
    else { float z = v * dw[0] + db[0]; out[idx] = 1.f / (1.f + __expf(-z)); }
}

extern "C" void kernel_launch(void* const* d_in, const int* in_sizes, int n_in,
                              void* d_out, int out_size, void* d_ws, size_t ws_size,
                              hipStream_t stream)
{
    const float* x  = (const float*)d_in[0];
    const float* W  = (const float*)d_in[1];
    const float* dw = (const float*)d_in[2];
    const float* db = (const float*)d_in[3];
    float* out = (float*)d_out;

    // pick largest split-k factor whose partial buffer fits ws
    const size_t perNic = 4 * 8192 * sizeof(float);   // 128KB per ic
    int nic = 0;
    const int cands[8] = {128, 64, 32, 16, 8, 4, 2, 1};
    for (int t = 0; t < 8; ++t) {
        if ((size_t)cands[t] * perNic + 2 * (size_t)SVD * 4 <= ws_size) { nic = cands[t]; break; }
    }

    if (nic > 0) {
        float* partial = (float*)d_ws;
        float* vA = partial + (size_t)nic * 32768;
        float* vB = vA + SVD;
        int ic_len = I_ / nic;
        dim3 grid(nic * 4), blk(256);

        route2<0, 0><<<grid, blk, 0, stream>>>(W, x, nullptr, partial, nic, ic_len);
        squash2<0><<<512, 64, 0, stream>>>(partial, nic, nullptr, vA, nullptr, nullptr, nullptr);
        route2<1, 0><<<grid, blk, 0, stream>>>(W, x, vA, partial, nic, ic_len);
        squash2<1><<<512, 64, 0, stream>>>(partial, nic, vA, vB, nullptr, nullptr, nullptr);
        route2<1, 0><<<grid, blk, 0, stream>>>(W, x, vB, partial, nic, ic_len);
        squash2<2><<<512, 64, 0, stream>>>(partial, nic, nullptr, nullptr, dw, db, out);
    } else {
        // tiny-ws fallback: atomic accumulate into s
        float* s  = (float*)d_ws;
        float* vA = s + SVD;
        float* vB = vA + SVD;
        hipMemsetAsync(s, 0, SVD * sizeof(float), stream);
        dim3 grid(512), blk(256);
        int sq_blocks = (SVD + 255) / 256;
        route2<0, 1><<<grid, blk, 0, stream>>>(W, x, nullptr, s, 128, 9);
        squashA<0><<<sq_blocks, 256, 0, stream>>>(s, nullptr, vA, nullptr, nullptr, nullptr);
        route2<1, 1><<<grid, blk, 0, stream>>>(W, x, vA, s, 128, 9);
        squashA<1><<<sq_blocks, 256, 0, stream>>>(s, vA, vB, nullptr, nullptr, nullptr);
        route2<1, 1><<<grid, blk, 0, stream>>>(W, x, vB, s, 128, 9);
        squashA<2><<<sq_blocks, 256, 0, stream>>>(s, nullptr, nullptr, dw, db, out);
    }
}